// Round 8
// baseline (114.135 us; speedup 1.0000x reference)
//
#include <hip/hip_runtime.h>
#include <math.h>

// Problem constants
#define BSZ   512
#define XD    768
#define YD    128
#define H2D   512

// Cost model (R6/R7 post-mortems): harness re-poisons the FULL 256 MiB d_ws
// every timed iteration (~41 us); each MB my kernels dirty adds ~0.17 us of
// dirty-line eviction to that fill. ws here: p1 16 MB + p2 4 MB = 20 MB.
// Fixed floor (fill + 10 input restores + memset + graph gaps) ~ 95 us.

// ---------------------------------------------------------------------------
// layer1: split-K x8 partials of x @ W1, both branches. NO bias/relu
// (applied in layer2 staging). x:(512,768) W1:(768,512)
//   -> p1[branch*8+ks][512][512]  (16 slices, 16 MB).
// Tile 128x128, 8x8 per thread = 1 LDS byte per MAC (vs 2 at 4x4 — the R7
// LDS-throughput wall). Per-thread rows {ty*4..+3, 64+ty*4..+3}, cols
// {tx*4..+3, 64+tx*4..+3}: all four fragment b128 reads are 16 unique addrs
// on stride-4 banks = 2-way max = free (R6's tx*8 4-way conflict fixed).
// K-tile 32, K-chunk 96 (3 tiles, register prefetch). Grid (4,4,16) = 256
// blocks, 1/CU — tolerable: barriers only every 2048 FMA-instrs.
// LDS 2x32x132x4 = 33.8 KB.
// ---------------------------------------------------------------------------
__global__ __launch_bounds__(256) void layer1_kernel(
    const float* __restrict__ x,
    const float* __restrict__ w1_mu, const float* __restrict__ w1_lv,
    float* __restrict__ p1)
{
    __shared__ float As[32][132];   // [k][m]
    __shared__ float Bs[32][132];   // [k][n]

    const int t      = threadIdx.x;
    const int branch = blockIdx.z >> 3;
    const int ks     = blockIdx.z & 7;
    const float* __restrict__ W = branch ? w1_lv : w1_mu;
    float* __restrict__ out = p1 + (size_t)blockIdx.z * (BSZ * H2D);

    const int m0 = blockIdx.x * 128;
    const int n0 = blockIdx.y * 128;
    const int tx = t & 15;
    const int ty = t >> 4;

    // staging maps:
    // A: row am = t&127, k-base akb = (t>>7)*16 (4 float4 along k, scattered
    //    into As -> 2-way bank pattern, free).
    // B: col bn = (t&31)*4, k-rows bk+8j (4 float4, contiguous b128 stores:
    //    lanes 0..31 write one full 512 B row).
    const int am  = t & 127;
    const int akb = (t >> 7) * 16;
    const int bn  = (t & 31) * 4;
    const int bk  = t >> 5;

    const int kbase = ks * 96;
    float acc[8][8] = {};

    float4 apf[4], bpf[4];
    {
        const float* xr = &x[(m0 + am) * XD + kbase + akb];
        #pragma unroll
        for (int j = 0; j < 4; ++j) apf[j] = *(const float4*)&xr[j * 4];
        #pragma unroll
        for (int j = 0; j < 4; ++j)
            bpf[j] = *(const float4*)&W[(kbase + bk + 8 * j) * H2D + n0 + bn];
    }

    for (int kt = 0; kt < 96; kt += 32) {
        __syncthreads();            // prev tile's readers done
        #pragma unroll
        for (int j = 0; j < 4; ++j) {
            As[akb + 4 * j + 0][am] = apf[j].x;
            As[akb + 4 * j + 1][am] = apf[j].y;
            As[akb + 4 * j + 2][am] = apf[j].z;
            As[akb + 4 * j + 3][am] = apf[j].w;
            *(float4*)&Bs[bk + 8 * j][bn] = bpf[j];
        }
        __syncthreads();
        if (kt + 32 < 96) {         // prefetch next tile under the FMAs
            const int kn = kbase + kt + 32;
            const float* xr = &x[(m0 + am) * XD + kn + akb];
            #pragma unroll
            for (int j = 0; j < 4; ++j) apf[j] = *(const float4*)&xr[j * 4];
            #pragma unroll
            for (int j = 0; j < 4; ++j)
                bpf[j] = *(const float4*)&W[(kn + bk + 8 * j) * H2D + n0 + bn];
        }
        #pragma unroll
        for (int k = 0; k < 32; ++k) {
            const float4 a0 = *(const float4*)&As[k][ty * 4];
            const float4 a1 = *(const float4*)&As[k][64 + ty * 4];
            const float4 b0 = *(const float4*)&Bs[k][tx * 4];
            const float4 b1 = *(const float4*)&Bs[k][64 + tx * 4];
            const float av[8] = {a0.x, a0.y, a0.z, a0.w, a1.x, a1.y, a1.z, a1.w};
            const float bv[8] = {b0.x, b0.y, b0.z, b0.w, b1.x, b1.y, b1.z, b1.w};
            #pragma unroll
            for (int i = 0; i < 8; ++i)
                #pragma unroll
                for (int j = 0; j < 8; ++j)
                    acc[i][j] += av[i] * bv[j];
        }
    }

    #pragma unroll
    for (int i = 0; i < 8; ++i) {
        const int row = m0 + (i >> 2) * 64 + ty * 4 + (i & 3);
        *(float4*)&out[row * H2D + n0 + tx * 4] =
            make_float4(acc[i][0], acc[i][1], acc[i][2], acc[i][3]);
        *(float4*)&out[row * H2D + n0 + 64 + tx * 4] =
            make_float4(acc[i][4], acc[i][5], acc[i][6], acc[i][7]);
    }
}

// ---------------------------------------------------------------------------
// layer2 (B-stationary, + ysum plane): split-K x8 partials of
// relu(sum_8 p1 + b1) @ W2 -> p2[branch*8+ks][512][128] (16 slices, 4 MB).
// Block = 32 m-rows x full N=128, K-chunk 64 as two 32-k register sub-chunks
// (B-regs: 2 cols/lane x 32 k = 64 VGPR). H-chunk (32x64) staged ONCE in LDS
// (8-slice sum + bias + relu), read as wave-uniform broadcast b128.
// Grid (16,1,17): z<16 GEMM (branch=z>>3, ks=z&7); z==16 = ysum plane
// (Sy/Sy2 fp64 + accum/counter init).
// ---------------------------------------------------------------------------
__global__ __launch_bounds__(256, 2) void layer2_kernel(
    const float* __restrict__ p1,
    const float* __restrict__ b1_mu, const float* __restrict__ b1_lv,
    const float* __restrict__ w2_mu, const float* __restrict__ w2_lv,
    const float* __restrict__ y,
    float* __restrict__ p2,
    double* __restrict__ Sy, double* __restrict__ Sy2,
    double* __restrict__ accum, unsigned int* __restrict__ counter)
{
    __shared__ float Hc[32][68];    // [m][k] 64+4 pad
    const int t = threadIdx.x;

    if (blockIdx.z == 16) {
        // ----- ysum plane: 16 blocks, 8 dims each -----
        const int id = blockIdx.x;
        const int dl = t & 7;
        const int g  = t >> 3;               // 0..31, 16 rows each
        const int d  = id * 8 + dl;
        float s = 0.f, s2 = 0.f;
        #pragma unroll
        for (int i = g * 16; i < g * 16 + 16; ++i) {
            const float v = y[i * YD + d];
            s += v; s2 += v * v;
        }
        float* shs  = &Hc[0][0];             // 2176 floats available
        float* shs2 = &Hc[0][0] + 512;
        shs[t] = s; shs2[t] = s2;
        __syncthreads();
        if (t < 8) {
            double S = 0.0, S2 = 0.0;
            #pragma unroll
            for (int gg = 0; gg < 32; ++gg) {
                S += (double)shs[gg * 8 + t]; S2 += (double)shs2[gg * 8 + t];
            }
            Sy[id * 8 + t] = S; Sy2[id * 8 + t] = S2;
        } else if (id == 0 && t == 8)  { accum[0] = 0.0; }
        else if (id == 0 && t == 9)  { accum[1] = 0.0; }
        else if (id == 0 && t == 10) { *counter = 0u; }
        return;
    }

    // ----- GEMM planes -----
    const int branch = blockIdx.z >> 3;
    const int ks     = blockIdx.z & 7;
    const float* __restrict__ q  = p1 + (size_t)(branch * 8) * (BSZ * H2D);
    const float* __restrict__ b1 = branch ? b1_lv : b1_mu;
    const float* __restrict__ W  = branch ? w2_lv : w2_mu;
    float* __restrict__ out = p2 + (size_t)blockIdx.z * (BSZ * YD);

    const int m0   = blockIdx.x * 32;
    const int kb   = ks * 64;
    const int lane = t & 63;
    const int wave = t >> 6;

    // Stage H chunk 32m x 64k: row = t>>3 (0..31), kq = (t&7)*8 (2 float4).
    // Sum 8 p1 slices + bias, relu.
    {
        const int row  = t >> 3;
        const int kq   = (t & 7) * 8;
        const int base = (m0 + row) * H2D + kb + kq;
        float4 h0 = *(const float4*)&b1[kb + kq];
        float4 h1 = *(const float4*)&b1[kb + kq + 4];
        #pragma unroll
        for (int s = 0; s < 8; ++s) {
            const float4 v0 = *(const float4*)&q[(size_t)s * (BSZ * H2D) + base];
            const float4 v1 = *(const float4*)&q[(size_t)s * (BSZ * H2D) + base + 4];
            h0.x += v0.x; h0.y += v0.y; h0.z += v0.z; h0.w += v0.w;
            h1.x += v1.x; h1.y += v1.y; h1.z += v1.z; h1.w += v1.w;
        }
        h0.x = fmaxf(h0.x, 0.f); h0.y = fmaxf(h0.y, 0.f);
        h0.z = fmaxf(h0.z, 0.f); h0.w = fmaxf(h0.w, 0.f);
        h1.x = fmaxf(h1.x, 0.f); h1.y = fmaxf(h1.y, 0.f);
        h1.z = fmaxf(h1.z, 0.f); h1.w = fmaxf(h1.w, 0.f);
        *(float4*)&Hc[row][kq]     = h0;
        *(float4*)&Hc[row][kq + 4] = h1;
    }
    __syncthreads();

    // Compute: wave owns m-rows wave*8..+7. B-chunk in registers, two 32-k
    // halves to bound live VGPRs.
    const int wm0 = wave * 8;
    float acc0[8] = {}, acc1[8] = {};
    #pragma unroll
    for (int half = 0; half < 2; ++half) {
        const int kh = kb + half * 32;
        float br0[32], br1[32];
        #pragma unroll
        for (int k = 0; k < 32; ++k) {
            br0[k] = W[(kh + k) * YD + lane];
            br1[k] = W[(kh + k) * YD + 64 + lane];
        }
        #pragma unroll
        for (int m = 0; m < 8; ++m) {
            const float* hrow = &Hc[wm0 + m][half * 32];
            #pragma unroll
            for (int qd = 0; qd < 8; ++qd) {
                const float4 a4 = *(const float4*)&hrow[qd * 4];
                acc0[m] += a4.x * br0[qd * 4 + 0]; acc1[m] += a4.x * br1[qd * 4 + 0];
                acc0[m] += a4.y * br0[qd * 4 + 1]; acc1[m] += a4.y * br1[qd * 4 + 1];
                acc0[m] += a4.z * br0[qd * 4 + 2]; acc1[m] += a4.z * br1[qd * 4 + 2];
                acc0[m] += a4.w * br0[qd * 4 + 3]; acc1[m] += a4.w * br1[qd * 4 + 3];
            }
        }
    }

    #pragma unroll
    for (int m = 0; m < 8; ++m) {
        const int row = (m0 + wm0 + m) * YD;
        out[row + lane]      = acc0[m];
        out[row + 64 + lane] = acc1[m];
    }
}

// ---------------------------------------------------------------------------
// reduce (+inline finalize): per element e=(i,d):
//   mu = sum_{s<8} p2[s][e] + b2_mu[d]; lv = tanh(sum_{s>=8} p2[s][e] + b2_lv[d])
//   iv = exp(-lv)
//   pos += -0.5*(mu-y)^2*iv - 0.5*lv
//   ap  += iv*(-0.5*Sy2[d] + mu*Sy[d] - 256*mu^2) - 256*lv
// fp32 elementwise, fp64 block reduction + device atomics; last block (atomic
// counter) finalizes: out = pos/B - ap/B^2 - log1p(exp(-20)/(B-1)).
// ---------------------------------------------------------------------------
__global__ __launch_bounds__(256) void reduce_kernel(
    const float* __restrict__ p2, const float* __restrict__ y,
    const float* __restrict__ b2_mu, const float* __restrict__ b2_lv,
    const double* __restrict__ Sy, const double* __restrict__ Sy2,
    double* __restrict__ accum, unsigned int* __restrict__ counter,
    float* __restrict__ outp)
{
    const int NE = BSZ * YD;
    const int e  = blockIdx.x * 256 + threadIdx.x;   // grid 256 covers exactly
    const int d  = e & (YD - 1);

    float mu = b2_mu[d];
    float lp = b2_lv[d];
    #pragma unroll
    for (int s = 0; s < 8; ++s) {
        mu += p2[s * NE + e];
        lp += p2[(8 + s) * NE + e];
    }
    const float lv = tanhf(lp);
    const float iv = expf(-lv);
    const float dm = mu - y[e];

    double pos = -0.5 * (double)dm * (double)dm * (double)iv - 0.5 * (double)lv;
    double ap  = (double)iv * (-0.5 * Sy2[d] + (double)mu * Sy[d]
                               - 256.0 * (double)mu * (double)mu)
               - 256.0 * (double)lv;

    #pragma unroll
    for (int off = 32; off > 0; off >>= 1) {
        pos += __shfl_down(pos, off);
        ap  += __shfl_down(ap, off);
    }
    __shared__ double sp[4];
    __shared__ double sa[4];
    const int lane = threadIdx.x & 63;
    const int wv   = threadIdx.x >> 6;
    if (lane == 0) { sp[wv] = pos; sa[wv] = ap; }
    __syncthreads();
    if (threadIdx.x == 0) {
        atomicAdd(&accum[0], sp[0] + sp[1] + sp[2] + sp[3]);
        atomicAdd(&accum[1], sa[0] + sa[1] + sa[2] + sa[3]);
        __threadfence();
        const unsigned int old = atomicAdd(counter, 1u);
        if (old == 255u) {                 // last block: finalize
            const double P = atomicAdd(&accum[0], 0.0);   // coherent read-back
            const double A = atomicAdd(&accum[1], 0.0);
            const double C = log1p(exp(-20.0) / 511.0);
            outp[0] = (float)(P / 512.0 - A / 262144.0 - C);
        }
    }
}

extern "C" void kernel_launch(void* const* d_in, const int* in_sizes, int n_in,
                              void* d_out, int out_size, void* d_ws, size_t ws_size,
                              hipStream_t stream) {
    const float* x     = (const float*)d_in[0];
    const float* y     = (const float*)d_in[1];
    const float* w1_mu = (const float*)d_in[2];
    const float* b1_mu = (const float*)d_in[3];
    const float* w2_mu = (const float*)d_in[4];
    const float* b2_mu = (const float*)d_in[5];
    const float* w1_lv = (const float*)d_in[6];
    const float* b1_lv = (const float*)d_in[7];
    const float* w2_lv = (const float*)d_in[8];
    const float* b2_lv = (const float*)d_in[9];

    char* ws = (char*)d_ws;
    float*  p1 = (float*)(ws);                                     // 16 MB (16 slices 512x512)
    float*  p2 = (float*)(ws + (size_t)16 * BSZ * H2D * 4);        // 4 MB (16 slices 512x128)
    double* Sy = (double*)(ws + (size_t)16 * BSZ * H2D * 4
                              + (size_t)16 * BSZ * YD * 4);        // 1 KB
    double* Sy2 = Sy + YD;                                         // 1 KB
    double* accum = Sy2 + YD;                                      // 16 B
    unsigned int* counter = (unsigned int*)(accum + 2);            // 4 B

    layer1_kernel<<<dim3(4, 4, 16), 256, 0, stream>>>(x, w1_mu, w1_lv, p1);
    layer2_kernel<<<dim3(16, 1, 17), 256, 0, stream>>>(
        p1, b1_mu, b1_lv, w2_mu, w2_lv, y, p2, Sy, Sy2, accum, counter);
    reduce_kernel<<<256, 256, 0, stream>>>(
        p2, y, b2_mu, b2_lv, Sy, Sy2, accum, counter, (float*)d_out);
}